// Round 8
// baseline (752.465 us; speedup 1.0000x reference)
//
#include <hip/hip_runtime.h>
#include <hip/hip_bf16.h>

#define NB 128
#define NS 1024
#define NE 256
#define NR 64
#define NO 1024
#define NK (NE*NR)   // 16384

typedef __attribute__((ext_vector_type(8))) short short8;          // MFMA A/B frag (8 bf16)
typedef __attribute__((ext_vector_type(4))) float float4v;         // MFMA C/D frag
typedef __attribute__((ext_vector_type(4))) unsigned short ushort4v;
typedef __attribute__((ext_vector_type(8))) unsigned short ushort8v;
typedef __attribute__((ext_vector_type(4))) unsigned int uint4v;

static __device__ inline unsigned short f2bf(float x) {
    union { float f; unsigned u; } v; v.f = x;
    unsigned r = v.u + 0x7fffu + ((v.u >> 16) & 1u);   // RNE
    return (unsigned short)(r >> 16);
}
static __device__ inline float bf2f(unsigned short h) {
    union { unsigned u; float f; } v; v.u = ((unsigned)h) << 16;
    return v.f;
}
// hardware RNE pair-convert; compiler fuses to v_cvt_pk_bf16_f32
static __device__ inline unsigned pk(float lo, float hi) {
    union { __hip_bfloat162 h2; unsigned u; } v;
    v.h2.x = __float2bfloat16(lo);
    v.h2.y = __float2bfloat16(hi);
    return v.u;
}

// ---------------------------------------------------------------------------
// k1 v3: parts[ch][b][e][r] = sum_{s-pairs p==ch mod 4, s<len} F[b,s,e]*R[b,s,r]
// VECTORIZED LDS staging (fix for scalar-load TA bound of r5):
//  - per K-step = 64 s (32 pairs): stage F-slice [32 pair][256 e] and R-slice
//    [32 pair][64 r] as packed-bf16-pair u32 into LDS.
//  - loads are float4 (10 dwordx4/thread/step, was 48 scalar/wave/step).
//  - roles staged ONCE per block (was loaded 8x redundantly by every wave).
//  - 1-deep reg prefetch: step t+1 loads issue before step t's MFMA phase.
//  - 16 MFMA per wave per 2 barriers. Padded LDS strides -> 2-way reads (free).
// grid NB*4 = 512 blocks, 512 thr (8 waves: we 0..3 = 64e, wn 0..1 = 32r).
// reps: idempotent measurement repeat.
// ---------------------------------------------------------------------------
#define NCH 4
#define PSTEP 32    // pairs per K-step (K=64 s)
#define SA 260      // A row stride in u32 (256 + 4 pad)
#define SB 68       // B row stride in u32 (64 + 4 pad)

__global__ __launch_bounds__(512, 4) void k1_mfma(
    const float* __restrict__ fillers, const float* __restrict__ roles,
    const int* __restrict__ lengths, unsigned short* __restrict__ parts,
    int reps)
{
    __shared__ unsigned As32[PSTEP * SA];   // 33.3 KB
    __shared__ unsigned Bs32[PSTEP * SB];   // 8.7 KB

    const int bid = blockIdx.x;
    const int b   = bid >> 2;
    const int ch  = bid & 3;
    const int len = lengths[b];
    const int tid = threadIdx.x;

    const int lane = tid & 63;
    const int wid  = tid >> 6;
    const int lrow = lane & 15;
    const int lgrp = lane >> 4;
    const int we   = wid >> 1;      // 0..3 : 64-e tile
    const int wn   = wid & 1;       // 0..1 : 32-r tile
    const int qb   = tid >> 4;      // B staging pair-row 0..31
    const int r4   = tid & 15;      // B staging r-group

    // pairs p = ch + 4*idx, idx < count; count <= 128 -> nsteps <= 4
    const int P      = (len + 1) >> 1;
    const int count  = (P > ch) ? ((P - ch + 3) >> 2) : 0;
    const int nsteps = (count + PSTEP - 1) >> 5;

    const float4 zf4 = make_float4(0.f, 0.f, 0.f, 0.f);
    const float* fb = fillers + (size_t)b * NS * NE;
    const float* rb = roles   + (size_t)b * NS * NR;
    unsigned short* pp = parts + (size_t)(ch * NB + b) * NK;

    for (int rep = 0; rep < reps; ++rep) {

        float4v acc[4][2];
        #pragma unroll
        for (int i = 0; i < 4; ++i)
            #pragma unroll
            for (int j = 0; j < 2; ++j)
                acc[i][j] = (float4v){0.f, 0.f, 0.f, 0.f};

        float4 Ast[4][2];   // 4 A-cells x (s0,s1)
        float4 Bst[2];      // 1 B-cell

        // stage-load step t into regs (all addresses structurally in-bounds:
        // p <= 511 -> s <= 1023; values with s>=len zeroed)
        #define K1_STAGE(t)                                                     \
        {                                                                       \
            const int base = (t) * PSTEP;                                       \
            const int smax = 2 * (ch + 4 * (base + 31)) + 1;                    \
            const bool edge = (smax >= len);   /* block-uniform */              \
            _Pragma("unroll")                                                   \
            for (int i = 0; i < 4; ++i) {                                       \
                const int c = tid + 512 * i;                                    \
                const int q = c >> 6, e4 = c & 63;                              \
                const int s0 = 2 * (ch + 4 * (base + q));                       \
                const float* f0 = fb + (size_t)s0 * NE + e4 * 4;                \
                float4 v0 = *(const float4*)f0;                                 \
                float4 v1 = *(const float4*)(f0 + NE);                          \
                if (edge) {                                                     \
                    if (s0     >= len) v0 = zf4;                                \
                    if (s0 + 1 >= len) v1 = zf4;                                \
                }                                                               \
                Ast[i][0] = v0; Ast[i][1] = v1;                                 \
            }                                                                   \
            {                                                                   \
                const int s0 = 2 * (ch + 4 * (base + qb));                      \
                const float* r0 = rb + (size_t)s0 * NR + r4 * 4;                \
                float4 v0 = *(const float4*)r0;                                 \
                float4 v1 = *(const float4*)(r0 + NR);                          \
                if (edge) {                                                     \
                    if (s0     >= len) v0 = zf4;                                \
                    if (s0 + 1 >= len) v1 = zf4;                                \
                }                                                               \
                Bst[0] = v0; Bst[1] = v1;                                       \
            }                                                                   \
        }

        if (nsteps > 0) K1_STAGE(0);

        for (int t = 0; t < nsteps; ++t) {
            __syncthreads();   // previous step's LDS reads complete

            // regs -> LDS (packed bf16 s-pairs, uint4 = contiguous 1KB/wave)
            #pragma unroll
            for (int i = 0; i < 4; ++i) {
                const int c = tid + 512 * i;
                const int q = c >> 6, e4 = c & 63;
                uint4v w;
                w.x = pk(Ast[i][0].x, Ast[i][1].x);
                w.y = pk(Ast[i][0].y, Ast[i][1].y);
                w.z = pk(Ast[i][0].z, Ast[i][1].z);
                w.w = pk(Ast[i][0].w, Ast[i][1].w);
                *(uint4v*)&As32[q * SA + e4 * 4] = w;
            }
            {
                uint4v w;
                w.x = pk(Bst[0].x, Bst[1].x);
                w.y = pk(Bst[0].y, Bst[1].y);
                w.z = pk(Bst[0].z, Bst[1].z);
                w.w = pk(Bst[0].w, Bst[1].w);
                *(uint4v*)&Bs32[qb * SB + r4 * 4] = w;
            }

            __syncthreads();   // LDS ready

            if (t + 1 < nsteps) K1_STAGE(t + 1);   // prefetch overlaps MFMA

            // MFMA: wave tile 64e x 32r, K=64 (2 half-steps of K=32)
            #pragma unroll
            for (int kk = 0; kk < 2; ++kk) {
                union { unsigned u[4]; short8 s8; } af[4], bf[2];
                #pragma unroll
                for (int mf = 0; mf < 4; ++mf) {
                    const int e = we * 64 + mf * 16 + lrow;
                    #pragma unroll
                    for (int jj = 0; jj < 4; ++jj)
                        af[mf].u[jj] = As32[(kk * 16 + lgrp * 4 + jj) * SA + e];
                }
                #pragma unroll
                for (int nf = 0; nf < 2; ++nf) {
                    const int r = wn * 32 + nf * 16 + lrow;
                    #pragma unroll
                    for (int jj = 0; jj < 4; ++jj)
                        bf[nf].u[jj] = Bs32[(kk * 16 + lgrp * 4 + jj) * SB + r];
                }
                #pragma unroll
                for (int mf = 0; mf < 4; ++mf)
                    #pragma unroll
                    for (int nf = 0; nf < 2; ++nf)
                        acc[mf][nf] = __builtin_amdgcn_mfma_f32_16x16x32_bf16(
                            af[mf].s8, bf[nf].s8, acc[mf][nf], 0, 0, 0);
            }
        }

        // epilogue: C/D col=lane&15 (r), row=(lane>>4)*4+reg (e).
        // Runs even when nsteps==0 (zero partial; ws is poisoned).
        #pragma unroll
        for (int mf = 0; mf < 4; ++mf) {
            #pragma unroll
            for (int nf = 0; nf < 2; ++nf) {
                const int r = wn * 32 + nf * 16 + lrow;
                #pragma unroll
                for (int reg = 0; reg < 4; ++reg) {
                    const int e = we * 64 + mf * 16 + lgrp * 4 + reg;
                    pp[(size_t)e * NR + r] = f2bf(acc[mf][nf][reg]);
                }
            }
        }
        #undef K1_STAGE
    }
}

// ---------------------------------------------------------------------------
// k1b: tensor[i] = bf16( sum_ch parts[ch][i] )
// ---------------------------------------------------------------------------
__global__ __launch_bounds__(256) void k1b_reduce(
    const unsigned short* __restrict__ parts, unsigned short* __restrict__ tensor)
{
    const size_t i = ((size_t)blockIdx.x * 256 + threadIdx.x) * 8;
    float s[8] = {0.f,0.f,0.f,0.f,0.f,0.f,0.f,0.f};
    #pragma unroll
    for (int ch = 0; ch < NCH; ++ch) {
        ushort8v v = *(const ushort8v*)(parts + (size_t)ch * NB * NK + i);
        #pragma unroll
        for (int j = 0; j < 8; ++j)
            s[j] += bf2f(v[j]);
    }
    ushort8v o;
    #pragma unroll
    for (int j = 0; j < 8; ++j)
        o[j] = f2bf(s[j]);
    *(ushort8v*)(tensor + i) = o;
}

// ---------------------------------------------------------------------------
// k2 v2: part[kz][b][o] = sum_{k in chunk kz} T[b][k] * W[o][k]
// BM=128 (=NB, W read once), BN=64, BK=128, KSPLIT=32.
// Changes vs r7: (a) 1-deep reg prefetch — step t+1 global loads issue before
// step t's MFMA phase (hides W HBM latency); (b) Bs staging writes are b128
// (2 cells of 8 bf16/row) instead of 8B 4-way-conflicting writes.
// ---------------------------------------------------------------------------
#define BN2 64
#define BK2 128
#define KSPLIT 32
#define KC2 (NK/KSPLIT)   // 512

__global__ __launch_bounds__(512) void k2_mfma(
    const unsigned short* __restrict__ A,   // tensor bf16 [NB][NK]
    const float* __restrict__ W,            // [NO][NK]
    float* __restrict__ part,               // [KSPLIT][NB][NO]
    int reps)
{
    __shared__ unsigned short As[128 * BK2];  // 32 KB, XOR-swizzled 256B rows
    __shared__ unsigned short Bs[BN2 * BK2];  // 16 KB

    const int o0   = blockIdx.x * BN2;
    const int kz   = blockIdx.y;
    const int tid  = threadIdx.x;
    const int lane = tid & 63;
    const int wid  = tid >> 6;
    const int wm   = wid >> 1;   // 0..3
    const int wn   = wid & 1;    // 0..1
    const int lrow = lane & 15;
    const int lgrp = lane >> 4;

    for (int rep = 0; rep < reps; ++rep) {

        float4v acc[2][2];
        #pragma unroll
        for (int i = 0; i < 2; ++i)
            #pragma unroll
            for (int j = 0; j < 2; ++j)
                acc[i][j] = (float4v){0.f, 0.f, 0.f, 0.f};

        ushort8v av[4];
        float4   wv[4];   // 2 cells x 2 float4 (same W row, k and k+4)

        #define K2_LOAD(step)                                                   \
        {                                                                       \
            const int kb = kz * KC2 + (step) * BK2;                             \
            _Pragma("unroll")                                                   \
            for (int i = 0; i < 4; ++i) {                                       \
                const int c = tid + 512 * i;                                    \
                const int r = c >> 4, c16 = c & 15;                             \
                av[i] = *(const ushort8v*)(A + (size_t)r * NK + kb + c16 * 8);  \
            }                                                                   \
            _Pragma("unroll")                                                   \
            for (int i = 0; i < 2; ++i) {                                       \
                const int c = tid + 512 * i;                                    \
                const int r = c >> 4, c8 = c & 15;                              \
                const float* wp = W + (size_t)(o0 + r) * NK + kb + c8 * 8;      \
                wv[2*i]   = *(const float4*)wp;                                 \
                wv[2*i+1] = *(const float4*)(wp + 4);                           \
            }                                                                   \
        }

        K2_LOAD(0);

        for (int step = 0; step < KC2 / BK2; ++step) {   // 4
            __syncthreads();   // LDS consumable

            #pragma unroll
            for (int i = 0; i < 4; ++i) {
                const int c = tid + 512 * i;
                const int r = c >> 4, c16 = c & 15;
                const int byte = (r * 256 + c16 * 16) ^ ((r & 7) << 4);
                *(ushort8v*)((char*)As + byte) = av[i];
            }
            #pragma unroll
            for (int i = 0; i < 2; ++i) {
                const int c = tid + 512 * i;
                const int r = c >> 4, c8 = c & 15;
                ushort8v bv;
                bv[0] = f2bf(wv[2*i].x);   bv[1] = f2bf(wv[2*i].y);
                bv[2] = f2bf(wv[2*i].z);   bv[3] = f2bf(wv[2*i].w);
                bv[4] = f2bf(wv[2*i+1].x); bv[5] = f2bf(wv[2*i+1].y);
                bv[6] = f2bf(wv[2*i+1].z); bv[7] = f2bf(wv[2*i+1].w);
                const int byte = (r * 256 + c8 * 16) ^ ((r & 7) << 4);
                *(ushort8v*)((char*)Bs + byte) = bv;
            }

            __syncthreads();   // LDS ready

            if (step + 1 < KC2 / BK2) K2_LOAD(step + 1);   // prefetch

            #pragma unroll
            for (int kk = 0; kk < BK2; kk += 32) {
                short8 af[2], bf[2];
                #pragma unroll
                for (int mf = 0; mf < 2; ++mf) {
                    const int r = wm * 32 + mf * 16 + lrow;
                    const int byte = (r * 256 + (kk + lgrp * 8) * 2) ^ ((r & 7) << 4);
                    af[mf] = *(const short8*)((const char*)As + byte);
                }
                #pragma unroll
                for (int nf = 0; nf < 2; ++nf) {
                    const int r = wn * 32 + nf * 16 + lrow;
                    const int byte = (r * 256 + (kk + lgrp * 8) * 2) ^ ((r & 7) << 4);
                    bf[nf] = *(const short8*)((const char*)Bs + byte);
                }
                #pragma unroll
                for (int mf = 0; mf < 2; ++mf)
                    #pragma unroll
                    for (int nf = 0; nf < 2; ++nf)
                        acc[mf][nf] = __builtin_amdgcn_mfma_f32_16x16x32_bf16(
                            af[mf], bf[nf], acc[mf][nf], 0, 0, 0);
            }
        }

        float* pbase = part + (size_t)kz * NB * NO;
        #pragma unroll
        for (int mf = 0; mf < 2; ++mf) {
            #pragma unroll
            for (int nf = 0; nf < 2; ++nf) {
                const int o = o0 + wn * 32 + nf * 16 + lrow;
                #pragma unroll
                for (int reg = 0; reg < 4; ++reg) {
                    const int m = wm * 32 + mf * 16 + lgrp * 4 + reg;
                    pbase[(size_t)m * NO + o] = acc[mf][nf][reg];
                }
            }
        }
        #undef K2_LOAD
    }
}

// ---------------------------------------------------------------------------
// k3: out[b][o] = bias[o] + sum_z part[z][b][o]
// ---------------------------------------------------------------------------
__global__ __launch_bounds__(256) void k3_reduce(
    const float* __restrict__ part, const float* __restrict__ bias,
    float* __restrict__ out)
{
    const int i = (blockIdx.x * 256 + threadIdx.x) * 4;
    float4 v = *(const float4*)(bias + (i & (NO - 1)));
    #pragma unroll
    for (int z = 0; z < KSPLIT; ++z) {
        float4 p = *(const float4*)(part + (size_t)z * NB * NO + i);
        v.x += p.x; v.y += p.y; v.z += p.z; v.w += p.w;
    }
    *(float4*)(out + i) = v;
}

extern "C" void kernel_launch(void* const* d_in, const int* in_sizes, int n_in,
                              void* d_out, int out_size, void* d_ws, size_t ws_size,
                              hipStream_t stream)
{
    const float* fillers = (const float*)d_in[0];
    const float* roles   = (const float*)d_in[1];
    const int*   lengths = (const int*)d_in[2];
    const float* W       = (const float*)d_in[3];
    const float* bias    = (const float*)d_in[4];
    float* out = (float*)d_out;

    // ws: [tensor bf16 4.19MB][parts bf16 4x4.19=16.8MB == overlaid part f32 16.8MB]
    unsigned short* tensor = (unsigned short*)d_ws;
    unsigned short* parts  = tensor + (size_t)NB * NK;   // k1 out, k1b in
    float*          part   = (float*)parts;              // k2 out, k3 in (disjoint lifetime)

    // MEASUREMENT ROUND 2: k1 reps=24 guarantees k1 rows outrank k2 rows and
    // the 75us fillBuffer dispatches in rocprof top-5; k2 reps=12 keeps its
    // rows above the fills too. Idempotent -> correctness unchanged.
    k1_mfma<<<NB * NCH, 512, 0, stream>>>(fillers, roles, lengths, parts, 24);
    k1b_reduce<<<(NB * NK / 8) / 256, 256, 0, stream>>>(parts, tensor);
    dim3 g2(NO / BN2, KSPLIT);   // (16, 32)
    k2_mfma<<<g2, 512, 0, stream>>>(tensor, W, part, 12);
    k3_reduce<<<(NB * NO) / 1024, 256, 0, stream>>>(part, bias, out);
}

// Round 9
// 87.123 us; speedup vs baseline: 8.6368x; 8.6368x over previous
//
#include <hip/hip_runtime.h>
#include <hip/hip_bf16.h>

#define NB 128
#define NS 1024
#define NE 256
#define NR 64
#define NO 1024
#define NK (NE*NR)   // 16384

typedef __attribute__((ext_vector_type(8))) short short8;          // MFMA A/B frag (8 bf16)
typedef __attribute__((ext_vector_type(4))) float float4v;         // MFMA C/D frag
typedef __attribute__((ext_vector_type(4))) unsigned short ushort4v;
typedef __attribute__((ext_vector_type(8))) unsigned short ushort8v;
typedef __attribute__((ext_vector_type(4))) unsigned int uint4v;

static __device__ inline unsigned short f2bf(float x) {
    union { float f; unsigned u; } v; v.f = x;
    unsigned r = v.u + 0x7fffu + ((v.u >> 16) & 1u);   // RNE
    return (unsigned short)(r >> 16);
}
static __device__ inline float bf2f(unsigned short h) {
    union { unsigned u; float f; } v; v.u = ((unsigned)h) << 16;
    return v.f;
}
// hardware RNE pair-convert; compiler fuses to v_cvt_pk_bf16_f32
static __device__ inline unsigned pk(float lo, float hi) {
    union { __hip_bfloat162 h2; unsigned u; } v;
    v.h2.x = __float2bfloat16(lo);
    v.h2.y = __float2bfloat16(hi);
    return v.u;
}

// ---------------------------------------------------------------------------
// k1 v4: WORK-STEALING over 1024 items (b, ch), NCH=8.
// parts[ch][b][e][r] = sum_{s-pairs p==ch mod 8, s<len} F[b,s,e]*R[b,s,r]
// 512 persistent worker blocks (2/CU) pull items via device atomic counter ->
// dynamic load balance (fixes the 2x static-makespan gap measured in r8:
// per-CU work was proportional to one batch's len).
// Inner structure = r8 v3: vectorized float4 staging, packed-bf16-pair LDS,
// 1-deep reg prefetch, 16 MFMA / 2 barriers, padded strides (2-way = free).
// Output location is item-owned -> deterministic despite dynamic assignment.
// ---------------------------------------------------------------------------
#define NCH 8
#define NITEMS (NB*NCH)   // 1024
#define NWORK  512        // worker blocks
#define PSTEP 32          // pairs per K-step (K=64 s)
#define SA 260            // A row stride in u32 (256 + 4 pad)
#define SB 68             // B row stride in u32 (64 + 4 pad)

__global__ __launch_bounds__(512, 4) void k1_mfma(
    const float* __restrict__ fillers, const float* __restrict__ roles,
    const int* __restrict__ lengths, unsigned short* __restrict__ parts,
    int* __restrict__ counter)
{
    __shared__ unsigned As32[PSTEP * SA];   // 33.3 KB
    __shared__ unsigned Bs32[PSTEP * SB];   // 8.7 KB
    __shared__ int s_idx;

    const int tid  = threadIdx.x;
    const int lane = tid & 63;
    const int wid  = tid >> 6;
    const int lrow = lane & 15;
    const int lgrp = lane >> 4;
    const int we   = wid >> 1;      // 0..3 : 64-e tile
    const int wn   = wid & 1;       // 0..1 : 32-r tile
    const int qb   = tid >> 4;      // B staging pair-row 0..31
    const int r4   = tid & 15;      // B staging r-group

    const float4 zf4 = make_float4(0.f, 0.f, 0.f, 0.f);

    for (;;) {
        __syncthreads();   // prior item's LDS reads done; s_idx reusable
        if (tid == 0) s_idx = atomicAdd(counter, 1);
        __syncthreads();
        const int idx = s_idx;
        if (idx >= NITEMS) break;   // block-uniform

        const int b   = idx >> 3;
        const int ch  = idx & 7;
        const int len = lengths[b];

        // pairs p = ch + 8*j, j < count; steps of 32 pairs -> nsteps <= 2
        const int P      = (len + 1) >> 1;
        const int count  = (P > ch) ? ((P - ch + 7) >> 3) : 0;
        const int nsteps = (count + PSTEP - 1) >> 5;

        const float* fb = fillers + (size_t)b * NS * NE;
        const float* rb = roles   + (size_t)b * NS * NR;
        unsigned short* pp = parts + (size_t)(ch * NB + b) * NK;

        float4v acc[4][2];
        #pragma unroll
        for (int i = 0; i < 4; ++i)
            #pragma unroll
            for (int j = 0; j < 2; ++j)
                acc[i][j] = (float4v){0.f, 0.f, 0.f, 0.f};

        float4 Ast[4][2];   // 4 A-cells x (s0,s1)
        float4 Bst[2];      // 1 B-cell

        // stage-load step t into regs (addresses structurally in-bounds:
        // p <= 511 -> s <= 1023; values with s>=len zeroed)
        #define K1_STAGE(t)                                                     \
        {                                                                       \
            const int base = (t) * PSTEP;                                       \
            const int smax = 2 * (ch + 8 * (base + 31)) + 1;                    \
            const bool edge = (smax >= len);   /* block-uniform */              \
            _Pragma("unroll")                                                   \
            for (int i = 0; i < 4; ++i) {                                       \
                const int c = tid + 512 * i;                                    \
                const int q = c >> 6, e4 = c & 63;                              \
                const int s0 = 2 * (ch + 8 * (base + q));                       \
                const float* f0 = fb + (size_t)s0 * NE + e4 * 4;                \
                float4 v0 = *(const float4*)f0;                                 \
                float4 v1 = *(const float4*)(f0 + NE);                          \
                if (edge) {                                                     \
                    if (s0     >= len) v0 = zf4;                                \
                    if (s0 + 1 >= len) v1 = zf4;                                \
                }                                                               \
                Ast[i][0] = v0; Ast[i][1] = v1;                                 \
            }                                                                   \
            {                                                                   \
                const int s0 = 2 * (ch + 8 * (base + qb));                      \
                const float* r0 = rb + (size_t)s0 * NR + r4 * 4;                \
                float4 v0 = *(const float4*)r0;                                 \
                float4 v1 = *(const float4*)(r0 + NR);                          \
                if (edge) {                                                     \
                    if (s0     >= len) v0 = zf4;                                \
                    if (s0 + 1 >= len) v1 = zf4;                                \
                }                                                               \
                Bst[0] = v0; Bst[1] = v1;                                       \
            }                                                                   \
        }

        if (nsteps > 0) K1_STAGE(0);

        for (int t = 0; t < nsteps; ++t) {
            __syncthreads();   // previous step's LDS reads complete

            // regs -> LDS (packed bf16 s-pairs, uint4 contiguous)
            #pragma unroll
            for (int i = 0; i < 4; ++i) {
                const int c = tid + 512 * i;
                const int q = c >> 6, e4 = c & 63;
                uint4v w;
                w.x = pk(Ast[i][0].x, Ast[i][1].x);
                w.y = pk(Ast[i][0].y, Ast[i][1].y);
                w.z = pk(Ast[i][0].z, Ast[i][1].z);
                w.w = pk(Ast[i][0].w, Ast[i][1].w);
                *(uint4v*)&As32[q * SA + e4 * 4] = w;
            }
            {
                uint4v w;
                w.x = pk(Bst[0].x, Bst[1].x);
                w.y = pk(Bst[0].y, Bst[1].y);
                w.z = pk(Bst[0].z, Bst[1].z);
                w.w = pk(Bst[0].w, Bst[1].w);
                *(uint4v*)&Bs32[qb * SB + r4 * 4] = w;
            }

            __syncthreads();   // LDS ready

            if (t + 1 < nsteps) K1_STAGE(t + 1);   // prefetch overlaps MFMA

            // MFMA: wave tile 64e x 32r, K=64 (2 half-steps of K=32)
            #pragma unroll
            for (int kk = 0; kk < 2; ++kk) {
                union { unsigned u[4]; short8 s8; } af[4], bf[2];
                #pragma unroll
                for (int mf = 0; mf < 4; ++mf) {
                    const int e = we * 64 + mf * 16 + lrow;
                    #pragma unroll
                    for (int jj = 0; jj < 4; ++jj)
                        af[mf].u[jj] = As32[(kk * 16 + lgrp * 4 + jj) * SA + e];
                }
                #pragma unroll
                for (int nf = 0; nf < 2; ++nf) {
                    const int r = wn * 32 + nf * 16 + lrow;
                    #pragma unroll
                    for (int jj = 0; jj < 4; ++jj)
                        bf[nf].u[jj] = Bs32[(kk * 16 + lgrp * 4 + jj) * SB + r];
                }
                #pragma unroll
                for (int mf = 0; mf < 4; ++mf)
                    #pragma unroll
                    for (int nf = 0; nf < 2; ++nf)
                        acc[mf][nf] = __builtin_amdgcn_mfma_f32_16x16x32_bf16(
                            af[mf].s8, bf[nf].s8, acc[mf][nf], 0, 0, 0);
            }
        }

        // epilogue: C/D col=lane&15 (r), row=(lane>>4)*4+reg (e).
        // Also runs when nsteps==0: zero partial (ws is poisoned).
        #pragma unroll
        for (int mf = 0; mf < 4; ++mf) {
            #pragma unroll
            for (int nf = 0; nf < 2; ++nf) {
                const int r = wn * 32 + nf * 16 + lrow;
                #pragma unroll
                for (int reg = 0; reg < 4; ++reg) {
                    const int e = we * 64 + mf * 16 + lgrp * 4 + reg;
                    pp[(size_t)e * NR + r] = f2bf(acc[mf][nf][reg]);
                }
            }
        }
        #undef K1_STAGE
    }
}

// ---------------------------------------------------------------------------
// k1b: tensor[i] = bf16( sum_ch parts[ch][i] )
// ---------------------------------------------------------------------------
__global__ __launch_bounds__(256) void k1b_reduce(
    const unsigned short* __restrict__ parts, unsigned short* __restrict__ tensor)
{
    const size_t i = ((size_t)blockIdx.x * 256 + threadIdx.x) * 8;
    float s[8] = {0.f,0.f,0.f,0.f,0.f,0.f,0.f,0.f};
    #pragma unroll
    for (int ch = 0; ch < NCH; ++ch) {
        ushort8v v = *(const ushort8v*)(parts + (size_t)ch * NB * NK + i);
        #pragma unroll
        for (int j = 0; j < 8; ++j)
            s[j] += bf2f(v[j]);
    }
    ushort8v o;
    #pragma unroll
    for (int j = 0; j < 8; ++j)
        o[j] = f2bf(s[j]);
    *(ushort8v*)(tensor + i) = o;
}

// ---------------------------------------------------------------------------
// k2 v2: part[kz][b][o] = sum_{k in chunk kz} T[b][k] * W[o][k]
// BM=128 (=NB, W read once), BN=64, BK=128, KSPLIT=32.
// 1-deep reg prefetch (step t+1 loads issue before step t's MFMAs);
// b128 LDS staging writes; XOR-swizzled rows (conflict-free reads).
// ---------------------------------------------------------------------------
#define BN2 64
#define BK2 128
#define KSPLIT 32
#define KC2 (NK/KSPLIT)   // 512

__global__ __launch_bounds__(512) void k2_mfma(
    const unsigned short* __restrict__ A,   // tensor bf16 [NB][NK]
    const float* __restrict__ W,            // [NO][NK]
    float* __restrict__ part)               // [KSPLIT][NB][NO]
{
    __shared__ unsigned short As[128 * BK2];  // 32 KB
    __shared__ unsigned short Bs[BN2 * BK2];  // 16 KB

    const int o0   = blockIdx.x * BN2;
    const int kz   = blockIdx.y;
    const int tid  = threadIdx.x;
    const int lane = tid & 63;
    const int wid  = tid >> 6;
    const int wm   = wid >> 1;   // 0..3
    const int wn   = wid & 1;    // 0..1
    const int lrow = lane & 15;
    const int lgrp = lane >> 4;

    float4v acc[2][2];
    #pragma unroll
    for (int i = 0; i < 2; ++i)
        #pragma unroll
        for (int j = 0; j < 2; ++j)
            acc[i][j] = (float4v){0.f, 0.f, 0.f, 0.f};

    ushort8v av[4];
    float4   wv[4];   // 2 cells x 2 float4 (same W row, k and k+4)

    #define K2_LOAD(step)                                                   \
    {                                                                       \
        const int kb = kz * KC2 + (step) * BK2;                             \
        _Pragma("unroll")                                                   \
        for (int i = 0; i < 4; ++i) {                                       \
            const int c = tid + 512 * i;                                    \
            const int r = c >> 4, c16 = c & 15;                             \
            av[i] = *(const ushort8v*)(A + (size_t)r * NK + kb + c16 * 8);  \
        }                                                                   \
        _Pragma("unroll")                                                   \
        for (int i = 0; i < 2; ++i) {                                       \
            const int c = tid + 512 * i;                                    \
            const int r = c >> 4, c8 = c & 15;                              \
            const float* wp = W + (size_t)(o0 + r) * NK + kb + c8 * 8;      \
            wv[2*i]   = *(const float4*)wp;                                 \
            wv[2*i+1] = *(const float4*)(wp + 4);                           \
        }                                                                   \
    }

    K2_LOAD(0);

    for (int step = 0; step < KC2 / BK2; ++step) {   // 4
        __syncthreads();   // prior step's LDS reads complete

        #pragma unroll
        for (int i = 0; i < 4; ++i) {
            const int c = tid + 512 * i;
            const int r = c >> 4, c16 = c & 15;
            const int byte = (r * 256 + c16 * 16) ^ ((r & 7) << 4);
            *(ushort8v*)((char*)As + byte) = av[i];
        }
        #pragma unroll
        for (int i = 0; i < 2; ++i) {
            const int c = tid + 512 * i;
            const int r = c >> 4, c8 = c & 15;
            ushort8v bv;
            bv[0] = f2bf(wv[2*i].x);   bv[1] = f2bf(wv[2*i].y);
            bv[2] = f2bf(wv[2*i].z);   bv[3] = f2bf(wv[2*i].w);
            bv[4] = f2bf(wv[2*i+1].x); bv[5] = f2bf(wv[2*i+1].y);
            bv[6] = f2bf(wv[2*i+1].z); bv[7] = f2bf(wv[2*i+1].w);
            const int byte = (r * 256 + c8 * 16) ^ ((r & 7) << 4);
            *(ushort8v*)((char*)Bs + byte) = bv;
        }

        __syncthreads();   // LDS ready

        if (step + 1 < KC2 / BK2) K2_LOAD(step + 1);   // prefetch

        #pragma unroll
        for (int kk = 0; kk < BK2; kk += 32) {
            short8 af[2], bf[2];
            #pragma unroll
            for (int mf = 0; mf < 2; ++mf) {
                const int r = wm * 32 + mf * 16 + lrow;
                const int byte = (r * 256 + (kk + lgrp * 8) * 2) ^ ((r & 7) << 4);
                af[mf] = *(const short8*)((const char*)As + byte);
            }
            #pragma unroll
            for (int nf = 0; nf < 2; ++nf) {
                const int r = wn * 32 + nf * 16 + lrow;
                const int byte = (r * 256 + (kk + lgrp * 8) * 2) ^ ((r & 7) << 4);
                bf[nf] = *(const short8*)((const char*)Bs + byte);
            }
            #pragma unroll
            for (int mf = 0; mf < 2; ++mf)
                #pragma unroll
                for (int nf = 0; nf < 2; ++nf)
                    acc[mf][nf] = __builtin_amdgcn_mfma_f32_16x16x32_bf16(
                        af[mf], bf[nf], acc[mf][nf], 0, 0, 0);
        }
    }

    float* pbase = part + (size_t)kz * NB * NO;
    #pragma unroll
    for (int mf = 0; mf < 2; ++mf) {
        #pragma unroll
        for (int nf = 0; nf < 2; ++nf) {
            const int o = o0 + wn * 32 + nf * 16 + lrow;
            #pragma unroll
            for (int reg = 0; reg < 4; ++reg) {
                const int m = wm * 32 + mf * 16 + lgrp * 4 + reg;
                pbase[(size_t)m * NO + o] = acc[mf][nf][reg];
            }
        }
    }
    #undef K2_LOAD
}

// ---------------------------------------------------------------------------
// k3: out[b][o] = bias[o] + sum_z part[z][b][o]
// ---------------------------------------------------------------------------
__global__ __launch_bounds__(256) void k3_reduce(
    const float* __restrict__ part, const float* __restrict__ bias,
    float* __restrict__ out)
{
    const int i = (blockIdx.x * 256 + threadIdx.x) * 4;
    float4 v = *(const float4*)(bias + (i & (NO - 1)));
    #pragma unroll
    for (int z = 0; z < KSPLIT; ++z) {
        float4 p = *(const float4*)(part + (size_t)z * NB * NO + i);
        v.x += p.x; v.y += p.y; v.z += p.z; v.w += p.w;
    }
    *(float4*)(out + i) = v;
}

extern "C" void kernel_launch(void* const* d_in, const int* in_sizes, int n_in,
                              void* d_out, int out_size, void* d_ws, size_t ws_size,
                              hipStream_t stream)
{
    const float* fillers = (const float*)d_in[0];
    const float* roles   = (const float*)d_in[1];
    const int*   lengths = (const int*)d_in[2];
    const float* W       = (const float*)d_in[3];
    const float* bias    = (const float*)d_in[4];
    float* out = (float*)d_out;

    // ws: [tensor bf16 4.19MB][parts bf16 8x4.19=33.6MB (k2's part f32 16.8MB
    //      overlays its front half; disjoint lifetimes)][counter 4B]
    unsigned short* tensor = (unsigned short*)d_ws;
    unsigned short* parts  = tensor + (size_t)NB * NK;
    float*          part   = (float*)parts;
    int* counter = (int*)((char*)d_ws
                   + (size_t)NB * NK * 2              // tensor
                   + (size_t)NCH * NB * NK * 2);      // parts

    hipMemsetAsync(counter, 0, sizeof(int), stream);  // stream-ordered, capture-safe
    k1_mfma<<<NWORK, 512, 0, stream>>>(fillers, roles, lengths, parts, counter);
    k1b_reduce<<<(NB * NK / 8) / 256, 256, 0, stream>>>(parts, tensor);
    dim3 g2(NO / BN2, KSPLIT);   // (16, 32)
    k2_mfma<<<g2, 512, 0, stream>>>(tensor, W, part);
    k3_reduce<<<(NB * NO) / 1024, 256, 0, stream>>>(part, bias, out);
}

// Round 10
// 62.435 us; speedup vs baseline: 12.0519x; 1.3954x over previous
//
#include <hip/hip_runtime.h>
#include <hip/hip_bf16.h>

#define NB 128
#define NS 1024
#define NE 256
#define NR 64
#define NO 1024
#define NK (NE*NR)   // 16384

typedef __attribute__((ext_vector_type(8))) short short8;          // MFMA A/B frag (8 bf16)
typedef __attribute__((ext_vector_type(4))) float float4v;         // MFMA C/D frag
typedef __attribute__((ext_vector_type(4))) unsigned short ushort4v;
typedef __attribute__((ext_vector_type(8))) unsigned short ushort8v;
typedef __attribute__((ext_vector_type(4))) unsigned int uint4v;

static __device__ inline unsigned short f2bf(float x) {
    union { float f; unsigned u; } v; v.f = x;
    unsigned r = v.u + 0x7fffu + ((v.u >> 16) & 1u);   // RNE
    return (unsigned short)(r >> 16);
}
static __device__ inline float bf2f(unsigned short h) {
    union { unsigned u; float f; } v; v.u = ((unsigned)h) << 16;
    return v.f;
}
// hardware RNE pair-convert; compiler fuses to v_cvt_pk_bf16_f32
static __device__ inline unsigned pk(float lo, float hi) {
    union { __hip_bfloat162 h2; unsigned u; } v;
    v.h2.x = __float2bfloat16(lo);
    v.h2.y = __float2bfloat16(hi);
    return v.u;
}

// ---------------------------------------------------------------------------
// k1 v5: STATIC grid with HW backfill (fixes r9's atomic-convoy disaster and
// r8's static-residency imbalance in one move).
// parts[ch][b][e][r] = sum_{s-pairs p==ch mod 8, s<len} F[b,s,e]*R[b,s,r]
// grid = NB*NCH = 1024 blocks > 768 resident (3/CU at 42KB LDS) -> command
// processor backfills greedily = dynamic balance without atomics.
// Inner loop = r8-measured vectorized structure: float4 staging, packed
// bf16-pair LDS, 1-deep reg prefetch, 16 MFMA / 2 barriers, padded strides.
// bid%8 == ch -> a batch's 8 chunks hit 8 XCDs with DISJOINT rows (no dup).
// ---------------------------------------------------------------------------
#define NCH 8
#define PSTEP 32          // pairs per K-step (K=64 s)
#define SA 260            // A row stride in u32 (256 + 4 pad)
#define SB 68             // B row stride in u32 (64 + 4 pad)

__global__ __launch_bounds__(512, 4) void k1_mfma(
    const float* __restrict__ fillers, const float* __restrict__ roles,
    const int* __restrict__ lengths, unsigned short* __restrict__ parts)
{
    __shared__ unsigned As32[PSTEP * SA];   // 33.3 KB
    __shared__ unsigned Bs32[PSTEP * SB];   // 8.7 KB

    const int bid = blockIdx.x;
    const int b   = bid >> 3;
    const int ch  = bid & 7;
    const int len = lengths[b];
    const int tid = threadIdx.x;

    const int lane = tid & 63;
    const int wid  = tid >> 6;
    const int lrow = lane & 15;
    const int lgrp = lane >> 4;
    const int we   = wid >> 1;      // 0..3 : 64-e tile
    const int wn   = wid & 1;       // 0..1 : 32-r tile
    const int qb   = tid >> 4;      // B staging pair-row 0..31
    const int r4   = tid & 15;      // B staging r-group

    // pairs p = ch + 8*j, j < count; steps of 32 pairs -> nsteps <= 2
    const int P      = (len + 1) >> 1;
    const int count  = (P > ch) ? ((P - ch + 7) >> 3) : 0;
    const int nsteps = (count + PSTEP - 1) >> 5;

    const float4 zf4 = make_float4(0.f, 0.f, 0.f, 0.f);
    const float* fb = fillers + (size_t)b * NS * NE;
    const float* rb = roles   + (size_t)b * NS * NR;
    unsigned short* pp = parts + (size_t)(ch * NB + b) * NK;

    float4v acc[4][2];
    #pragma unroll
    for (int i = 0; i < 4; ++i)
        #pragma unroll
        for (int j = 0; j < 2; ++j)
            acc[i][j] = (float4v){0.f, 0.f, 0.f, 0.f};

    float4 Ast[4][2];   // 4 A-cells x (s0,s1)
    float4 Bst[2];      // 1 B-cell

    // stage-load step t into regs (addresses structurally in-bounds:
    // p <= 511 -> s <= 1023; values with s>=len zeroed)
    #define K1_STAGE(t)                                                     \
    {                                                                       \
        const int base = (t) * PSTEP;                                       \
        const int smax = 2 * (ch + 8 * (base + 31)) + 1;                    \
        const bool edge = (smax >= len);   /* block-uniform */              \
        _Pragma("unroll")                                                   \
        for (int i = 0; i < 4; ++i) {                                       \
            const int c = tid + 512 * i;                                    \
            const int q = c >> 6, e4 = c & 63;                              \
            const int s0 = 2 * (ch + 8 * (base + q));                       \
            const float* f0 = fb + (size_t)s0 * NE + e4 * 4;                \
            float4 v0 = *(const float4*)f0;                                 \
            float4 v1 = *(const float4*)(f0 + NE);                          \
            if (edge) {                                                     \
                if (s0     >= len) v0 = zf4;                                \
                if (s0 + 1 >= len) v1 = zf4;                                \
            }                                                               \
            Ast[i][0] = v0; Ast[i][1] = v1;                                 \
        }                                                                   \
        {                                                                   \
            const int s0 = 2 * (ch + 8 * (base + qb));                      \
            const float* r0 = rb + (size_t)s0 * NR + r4 * 4;                \
            float4 v0 = *(const float4*)r0;                                 \
            float4 v1 = *(const float4*)(r0 + NR);                          \
            if (edge) {                                                     \
                if (s0     >= len) v0 = zf4;                                \
                if (s0 + 1 >= len) v1 = zf4;                                \
            }                                                               \
            Bst[0] = v0; Bst[1] = v1;                                       \
        }                                                                   \
    }

    if (nsteps > 0) K1_STAGE(0);

    for (int t = 0; t < nsteps; ++t) {
        __syncthreads();   // previous step's LDS reads complete

        // regs -> LDS (packed bf16 s-pairs, uint4 contiguous)
        #pragma unroll
        for (int i = 0; i < 4; ++i) {
            const int c = tid + 512 * i;
            const int q = c >> 6, e4 = c & 63;
            uint4v w;
            w.x = pk(Ast[i][0].x, Ast[i][1].x);
            w.y = pk(Ast[i][0].y, Ast[i][1].y);
            w.z = pk(Ast[i][0].z, Ast[i][1].z);
            w.w = pk(Ast[i][0].w, Ast[i][1].w);
            *(uint4v*)&As32[q * SA + e4 * 4] = w;
        }
        {
            uint4v w;
            w.x = pk(Bst[0].x, Bst[1].x);
            w.y = pk(Bst[0].y, Bst[1].y);
            w.z = pk(Bst[0].z, Bst[1].z);
            w.w = pk(Bst[0].w, Bst[1].w);
            *(uint4v*)&Bs32[qb * SB + r4 * 4] = w;
        }

        __syncthreads();   // LDS ready

        if (t + 1 < nsteps) K1_STAGE(t + 1);   // prefetch overlaps MFMA

        // MFMA: wave tile 64e x 32r, K=64 (2 half-steps of K=32)
        #pragma unroll
        for (int kk = 0; kk < 2; ++kk) {
            union { unsigned u[4]; short8 s8; } af[4], bf[2];
            #pragma unroll
            for (int mf = 0; mf < 4; ++mf) {
                const int e = we * 64 + mf * 16 + lrow;
                #pragma unroll
                for (int jj = 0; jj < 4; ++jj)
                    af[mf].u[jj] = As32[(kk * 16 + lgrp * 4 + jj) * SA + e];
            }
            #pragma unroll
            for (int nf = 0; nf < 2; ++nf) {
                const int r = wn * 32 + nf * 16 + lrow;
                #pragma unroll
                for (int jj = 0; jj < 4; ++jj)
                    bf[nf].u[jj] = Bs32[(kk * 16 + lgrp * 4 + jj) * SB + r];
            }
            #pragma unroll
            for (int mf = 0; mf < 4; ++mf)
                #pragma unroll
                for (int nf = 0; nf < 2; ++nf)
                    acc[mf][nf] = __builtin_amdgcn_mfma_f32_16x16x32_bf16(
                        af[mf].s8, bf[nf].s8, acc[mf][nf], 0, 0, 0);
        }
    }

    // epilogue: C/D col=lane&15 (r), row=(lane>>4)*4+reg (e).
    // Also runs when nsteps==0: zero partial (ws is poisoned).
    #pragma unroll
    for (int mf = 0; mf < 4; ++mf) {
        #pragma unroll
        for (int nf = 0; nf < 2; ++nf) {
            const int r = wn * 32 + nf * 16 + lrow;
            #pragma unroll
            for (int reg = 0; reg < 4; ++reg) {
                const int e = we * 64 + mf * 16 + lgrp * 4 + reg;
                pp[(size_t)e * NR + r] = f2bf(acc[mf][nf][reg]);
            }
        }
    }
    #undef K1_STAGE
}

// ---------------------------------------------------------------------------
// k1b: tensor[i] = bf16( sum_ch parts[ch][i] )
// ---------------------------------------------------------------------------
__global__ __launch_bounds__(256) void k1b_reduce(
    const unsigned short* __restrict__ parts, unsigned short* __restrict__ tensor)
{
    const size_t i = ((size_t)blockIdx.x * 256 + threadIdx.x) * 8;
    float s[8] = {0.f,0.f,0.f,0.f,0.f,0.f,0.f,0.f};
    #pragma unroll
    for (int ch = 0; ch < NCH; ++ch) {
        ushort8v v = *(const ushort8v*)(parts + (size_t)ch * NB * NK + i);
        #pragma unroll
        for (int j = 0; j < 8; ++j)
            s[j] += bf2f(v[j]);
    }
    ushort8v o;
    #pragma unroll
    for (int j = 0; j < 8; ++j)
        o[j] = f2bf(s[j]);
    *(ushort8v*)(tensor + i) = o;
}

// ---------------------------------------------------------------------------
// k2 v2: part[kz][b][o] = sum_{k in chunk kz} T[b][k] * W[o][k]
// BM=128 (=NB, W read once), BN=64, BK=128, KSPLIT=32.
// 1-deep reg prefetch; b128 LDS staging writes; XOR-swizzled rows.
// ---------------------------------------------------------------------------
#define BN2 64
#define BK2 128
#define KSPLIT 32
#define KC2 (NK/KSPLIT)   // 512

__global__ __launch_bounds__(512) void k2_mfma(
    const unsigned short* __restrict__ A,   // tensor bf16 [NB][NK]
    const float* __restrict__ W,            // [NO][NK]
    float* __restrict__ part)               // [KSPLIT][NB][NO]
{
    __shared__ unsigned short As[128 * BK2];  // 32 KB
    __shared__ unsigned short Bs[BN2 * BK2];  // 16 KB

    const int o0   = blockIdx.x * BN2;
    const int kz   = blockIdx.y;
    const int tid  = threadIdx.x;
    const int lane = tid & 63;
    const int wid  = tid >> 6;
    const int wm   = wid >> 1;   // 0..3
    const int wn   = wid & 1;    // 0..1
    const int lrow = lane & 15;
    const int lgrp = lane >> 4;

    float4v acc[2][2];
    #pragma unroll
    for (int i = 0; i < 2; ++i)
        #pragma unroll
        for (int j = 0; j < 2; ++j)
            acc[i][j] = (float4v){0.f, 0.f, 0.f, 0.f};

    ushort8v av[4];
    float4   wv[4];   // 2 cells x 2 float4 (same W row, k and k+4)

    #define K2_LOAD(step)                                                   \
    {                                                                       \
        const int kb = kz * KC2 + (step) * BK2;                             \
        _Pragma("unroll")                                                   \
        for (int i = 0; i < 4; ++i) {                                       \
            const int c = tid + 512 * i;                                    \
            const int r = c >> 4, c16 = c & 15;                             \
            av[i] = *(const ushort8v*)(A + (size_t)r * NK + kb + c16 * 8);  \
        }                                                                   \
        _Pragma("unroll")                                                   \
        for (int i = 0; i < 2; ++i) {                                       \
            const int c = tid + 512 * i;                                    \
            const int r = c >> 4, c8 = c & 15;                              \
            const float* wp = W + (size_t)(o0 + r) * NK + kb + c8 * 8;      \
            wv[2*i]   = *(const float4*)wp;                                 \
            wv[2*i+1] = *(const float4*)(wp + 4);                           \
        }                                                                   \
    }

    K2_LOAD(0);

    for (int step = 0; step < KC2 / BK2; ++step) {   // 4
        __syncthreads();   // prior step's LDS reads complete

        #pragma unroll
        for (int i = 0; i < 4; ++i) {
            const int c = tid + 512 * i;
            const int r = c >> 4, c16 = c & 15;
            const int byte = (r * 256 + c16 * 16) ^ ((r & 7) << 4);
            *(ushort8v*)((char*)As + byte) = av[i];
        }
        #pragma unroll
        for (int i = 0; i < 2; ++i) {
            const int c = tid + 512 * i;
            const int r = c >> 4, c8 = c & 15;
            ushort8v bv;
            bv[0] = f2bf(wv[2*i].x);   bv[1] = f2bf(wv[2*i].y);
            bv[2] = f2bf(wv[2*i].z);   bv[3] = f2bf(wv[2*i].w);
            bv[4] = f2bf(wv[2*i+1].x); bv[5] = f2bf(wv[2*i+1].y);
            bv[6] = f2bf(wv[2*i+1].z); bv[7] = f2bf(wv[2*i+1].w);
            const int byte = (r * 256 + c8 * 16) ^ ((r & 7) << 4);
            *(ushort8v*)((char*)Bs + byte) = bv;
        }

        __syncthreads();   // LDS ready

        if (step + 1 < KC2 / BK2) K2_LOAD(step + 1);   // prefetch

        #pragma unroll
        for (int kk = 0; kk < BK2; kk += 32) {
            short8 af[2], bf[2];
            #pragma unroll
            for (int mf = 0; mf < 2; ++mf) {
                const int r = wm * 32 + mf * 16 + lrow;
                const int byte = (r * 256 + (kk + lgrp * 8) * 2) ^ ((r & 7) << 4);
                af[mf] = *(const short8*)((const char*)As + byte);
            }
            #pragma unroll
            for (int nf = 0; nf < 2; ++nf) {
                const int r = wn * 32 + nf * 16 + lrow;
                const int byte = (r * 256 + (kk + lgrp * 8) * 2) ^ ((r & 7) << 4);
                bf[nf] = *(const short8*)((const char*)Bs + byte);
            }
            #pragma unroll
            for (int mf = 0; mf < 2; ++mf)
                #pragma unroll
                for (int nf = 0; nf < 2; ++nf)
                    acc[mf][nf] = __builtin_amdgcn_mfma_f32_16x16x32_bf16(
                        af[mf], bf[nf], acc[mf][nf], 0, 0, 0);
        }
    }

    float* pbase = part + (size_t)kz * NB * NO;
    #pragma unroll
    for (int mf = 0; mf < 2; ++mf) {
        #pragma unroll
        for (int nf = 0; nf < 2; ++nf) {
            const int o = o0 + wn * 32 + nf * 16 + lrow;
            #pragma unroll
            for (int reg = 0; reg < 4; ++reg) {
                const int m = wm * 32 + mf * 16 + lgrp * 4 + reg;
                pbase[(size_t)m * NO + o] = acc[mf][nf][reg];
            }
        }
    }
    #undef K2_LOAD
}

// ---------------------------------------------------------------------------
// k3: out[b][o] = bias[o] + sum_z part[z][b][o]
// ---------------------------------------------------------------------------
__global__ __launch_bounds__(256) void k3_reduce(
    const float* __restrict__ part, const float* __restrict__ bias,
    float* __restrict__ out)
{
    const int i = (blockIdx.x * 256 + threadIdx.x) * 4;
    float4 v = *(const float4*)(bias + (i & (NO - 1)));
    #pragma unroll
    for (int z = 0; z < KSPLIT; ++z) {
        float4 p = *(const float4*)(part + (size_t)z * NB * NO + i);
        v.x += p.x; v.y += p.y; v.z += p.z; v.w += p.w;
    }
    *(float4*)(out + i) = v;
}

extern "C" void kernel_launch(void* const* d_in, const int* in_sizes, int n_in,
                              void* d_out, int out_size, void* d_ws, size_t ws_size,
                              hipStream_t stream)
{
    const float* fillers = (const float*)d_in[0];
    const float* roles   = (const float*)d_in[1];
    const int*   lengths = (const int*)d_in[2];
    const float* W       = (const float*)d_in[3];
    const float* bias    = (const float*)d_in[4];
    float* out = (float*)d_out;

    // ws: [tensor bf16 4.19MB][parts bf16 8x4.19=33.6MB (k2's part f32 16.8MB
    //      overlays its front half; disjoint lifetimes)]
    unsigned short* tensor = (unsigned short*)d_ws;
    unsigned short* parts  = tensor + (size_t)NB * NK;
    float*          part   = (float*)parts;

    k1_mfma<<<NB * NCH, 512, 0, stream>>>(fillers, roles, lengths, parts);
    k1b_reduce<<<(NB * NK / 8) / 256, 256, 0, stream>>>(parts, tensor);
    dim3 g2(NO / BN2, KSPLIT);   // (16, 32)
    k2_mfma<<<g2, 512, 0, stream>>>(tensor, W, part);
    k3_reduce<<<(NB * NO) / 1024, 256, 0, stream>>>(part, bias, out);
}